// Round 13
// baseline (205.751 us; speedup 1.0000x reference)
//
#include <hip/hip_runtime.h>

// 1D Euler, Roe flux + Harten entropy fix, 32 fused steps. Round 27:
// r26 (early seam publish + lightweight ordering) = 118.3us, best. busy*dur
// constant ~69us since r23 => genuine work; stall ~1.5us/step remains.
// Reading r26 as data: WAVE 0 carries every global RT in series -- tid0's
// seam poll (lane-divergent, all 64 lanes wait), then flux, then the dt
// poll in E (~600cy), and post-BAR2 the bmax publish (tid<16 = wave0).
// Waves 1-14 only flux. BAR1 spread ~= wave0's serialized extra.
// r27 distributes the duties (no protocol/numeric change):
//  1. dt poll -> wave 4, loads PRE-ISSUED at step top, consumed pre-BAR1
//     (~2us of flux hides the RT; fallback loop kept). Same row, same
//     reduction tree => bit-identical dt.
//  2. bmax publish -> wave 8 (wid==8, lane<16, red[lane], same tree).
//     Wave0 starts step k+1's seam poll right after BAR2.
//  3. tid0/tid1023 keep their seam polls (inherent to their flux0/flux4).
// Seam RT (wave0/wave15), dt RT (wave4), publish (wave8) now overlap.
// Everything else byte-for-byte r26: ring protocol w/ vmcnt drain, packed
// roe2, slack dt row, XCD swizzle, 2 barriers, sentinel init.

#define NXC   1048576
#define GAM   1.4f
#define GM1   0.4f
#define IGM1  2.5f
#define CFLC  0.5f
#define DXC   1e-3f
#define IDXC  1000.0f
#define EFIX  0.1f
#define NSTEPS 32
#define NSLOT  (NSTEPS + 1)

#define ABLK  1024
#define ACPT  4
#define ATILE (ABLK*ACPT)      // 4096
#define ANBLK (NXC/ATILE)      // 256 blocks = 1/CU (proven residency)

#define CTRL_TOTAL (NSLOT * ANBLK)          // bmax flag words
#define RING_U64   (4 * ANBLK * 2 * 2)      // 4 rows x 256 blk x 2 edges x 2 words
#define INIT_WORDS (CTRL_TOTAL + RING_U64 * 2)

typedef float f2 __attribute__((ext_vector_type(2)));
typedef unsigned long long u64;

__device__ __forceinline__ float frcp(float x){ return __builtin_amdgcn_rcpf(x); }
__device__ __forceinline__ float frsq(float x){ return __builtin_amdgcn_rsqf(x); }
__device__ __forceinline__ float fsqrt_(float x){ return __builtin_amdgcn_sqrtf(x); }

__device__ __forceinline__ f2 mkf2(float a, float b){ f2 v; v.x=a; v.y=b; return v; }
__device__ __forceinline__ f2 f2rcp(f2 a){ return mkf2(frcp(a.x), frcp(a.y)); }
__device__ __forceinline__ f2 f2rsq(f2 a){ return mkf2(frsq(a.x), frsq(a.y)); }
__device__ __forceinline__ f2 f2sqrt(f2 a){ return mkf2(fsqrt_(a.x), fsqrt_(a.y)); }
__device__ __forceinline__ f2 f2max(f2 a, f2 b){
    return mkf2(fmaxf(a.x,b.x), fmaxf(a.y,b.y));
}
__device__ __forceinline__ f2 f2abs(f2 a){
    return mkf2(fabsf(a.x), fabsf(a.y));
}

// Device (agent) scope RELAXED atomics only -- no acq/rel machinery.
__device__ __forceinline__ unsigned devloadu(const unsigned* p) {
    return __hip_atomic_load(p, __ATOMIC_RELAXED, __HIP_MEMORY_SCOPE_AGENT);
}
__device__ __forceinline__ void devstoreu(unsigned* p, unsigned v) {
    __hip_atomic_store(p, v, __ATOMIC_RELAXED, __HIP_MEMORY_SCOPE_AGENT);
}
__device__ __forceinline__ u64 ld_rlx64(const u64* p) {
    return __hip_atomic_load(p, __ATOMIC_RELAXED, __HIP_MEMORY_SCOPE_AGENT);
}
__device__ __forceinline__ void st_rlx64(u64* p, u64 v) {
    __hip_atomic_store(p, v, __ATOMIC_RELAXED, __HIP_MEMORY_SCOPE_AGENT);
}
__device__ __forceinline__ void drain_vmem() {
    // Producer-side ordering: data word complete at the coherence point
    // before the tag word issues (the proven r26 mechanism).
    asm volatile("s_waitcnt vmcnt(0)" ::: "memory");
}
__device__ __forceinline__ u64 pack2f(float a, float b) {
    return (u64)__float_as_uint(a) | ((u64)__float_as_uint(b) << 32);
}
__device__ __forceinline__ u64 packft(float a, unsigned tag) {
    return (u64)__float_as_uint(a) | ((u64)tag << 32);
}

__device__ __forceinline__ float wave_max(float v) {
    #pragma unroll
    for (int k = 32; k >= 1; k >>= 1)
        v = fmaxf(v, __shfl_xor(v, k));
    return v;
}

// Sentinel init: bmax flags sign-SET ("unpublished"); ring tags != any k.
__global__ void ctrl_init(unsigned* z) {
    int i = blockIdx.x * 256 + threadIdx.x;
    if (i < INIT_WORDS) z[i] = 0xAAAAAAAAu;
}

// Scalar Roe flux (right-edge interface only).
__device__ __forceinline__ void roe(
        float rL, float uL, float pL, float sL, float gL,
        float rR, float uR, float pR, float sR, float gR,
        float& Frj, float& Fmj, float& Fej) {
    float invden = frcp(sL + sR);
    float ur = (sL * uL + sR * uR) * invden;
    float Hr = (gL + gR) * invden;
    float c2u = fmaxf(GM1 * (Hr - 0.5f * ur * ur), 1e-10f);
    float qc = frsq(c2u);
    float c  = c2u * qc;
    float inv2c2 = 0.5f * qc * qc;
    float eps = EFIX * c;
    float l1 = ur - c, l3 = ur + c;
    float a1 = fsqrt_(l1 * l1 + eps * eps);
    float a2 = fsqrt_(ur * ur + eps * eps);
    float a3 = fsqrt_(l3 * l3 + eps * eps);
    float drho = rR - rL;
    float du   = uR - uL;
    float dp   = pR - pL;
    float al2 = drho - (dp + dp) * inv2c2;
    float tcd = c * rR * du;
    float al1 = (dp - tcd) * inv2c2;
    float al3 = (dp + tcd) * inv2c2;
    float FrL = rL * uL, FrR = rR * uR;
    float FmL = FrL * uL + pL, FmR = FrR * uR + pR;
    float FeL = uL * (gL * sL), FeR = uR * (gR * sR);
    float w1 = a1 * al1, w2 = a2 * al2, w3 = a3 * al3;
    Frj = 0.5f * (FrL + FrR - (w1 + w2 + w3));
    Fmj = 0.5f * (FmL + FmR - (w1 * l1 + w2 * ur + w3 * l3));
    Fej = 0.5f * (FeL + FeR - (w1 * (Hr - ur * c) + w2 * (0.5f * ur * ur)
                               + w3 * (Hr + ur * c)));
}

// Packed Roe flux: two independent interfaces per call (v_pk_* fp32 path).
__device__ __forceinline__ void roe2(
        f2 rL, f2 uL, f2 pL, f2 sL, f2 gL,
        f2 rR, f2 uR, f2 pR, f2 sR, f2 gR,
        f2& Frj, f2& Fmj, f2& Fej) {
    f2 invden = f2rcp(sL + sR);
    f2 ur = (sL * uL + sR * uR) * invden;
    f2 Hr = (gL + gR) * invden;
    f2 c2u = f2max(GM1 * (Hr - 0.5f * ur * ur), mkf2(1e-10f, 1e-10f));
    f2 qc = f2rsq(c2u);
    f2 c  = c2u * qc;
    f2 inv2c2 = 0.5f * qc * qc;
    f2 eps = EFIX * c;
    f2 l1 = ur - c, l3 = ur + c;
    f2 a1 = f2sqrt(l1 * l1 + eps * eps);
    f2 a2 = f2sqrt(ur * ur + eps * eps);
    f2 a3 = f2sqrt(l3 * l3 + eps * eps);
    f2 drho = rR - rL;
    f2 du   = uR - uL;
    f2 dp   = pR - pL;
    f2 al2 = drho - (dp + dp) * inv2c2;
    f2 tcd = c * rR * du;
    f2 al1 = (dp - tcd) * inv2c2;
    f2 al3 = (dp + tcd) * inv2c2;
    f2 FrL = rL * uL, FrR = rR * uR;
    f2 FmL = FrL * uL + pL, FmR = FrR * uR + pR;
    f2 FeL = uL * (gL * sL), FeR = uR * (gR * sR);
    f2 w1 = a1 * al1, w2 = a2 * al2, w3 = a3 * al3;
    Frj = 0.5f * (FrL + FrR - (w1 + w2 + w3));
    Fmj = 0.5f * (FmL + FmR - (w1 * l1 + w2 * ur + w3 * l3));
    Fej = 0.5f * (FeL + FeR - (w1 * (Hr - ur * c) + w2 * (0.5f * ur * ur)
                               + w3 * (Hr + ur * c)));
}

// ring layout: [(row&3)][block][edge][word]; edge 0 = cell0 (left),
// edge 1 = cell3 (right); word 0 = {r,u}, word 1 = {p, tag}.
__device__ __forceinline__ u64* ring_pkt(u64* ring, int row, int blk, int edge) {
    return ring + (((size_t)(row & 3) * ANBLK + blk) * 2 + edge) * 2;
}

__global__ __launch_bounds__(ABLK, 4) void euler_async(
        const float* __restrict__ rho0, const float* __restrict__ u0,
        const float* __restrict__ p0, const float* __restrict__ tf,
        float* __restrict__ out, unsigned* __restrict__ bmax,
        u64* __restrict__ ring) {
    __shared__ float Lr[ABLK], Lu[ABLK], Lp[ABLK];    // each thread's cell3
    __shared__ float fxr[ABLK], fxm[ABLK], fxe[ABLK]; // each thread's flux0
    __shared__ float red[ABLK / 64];
    __shared__ float samax;

    const int tid = threadIdx.x;
    // XCD swizzle (kept from r18: time-neutral, lowers L2 misses).
    const int lb = (blockIdx.x & 7) * (ANBLK / 8) + (blockIdx.x >> 3);
    const int c0 = lb * ATILE + ACPT * tid;
    const int lane = tid & 63, wid = tid >> 6;

    float cr[4], cu[4], cp[4], cE[4], cs[4], cg[4];

    // ---- prepass: inputs -> regs (incl E,s,g); publish seam row 0 +
    // bmax row 0 --
    {
        float4 r4 = *(const float4*)(rho0 + c0);
        float4 u4 = *(const float4*)(u0 + c0);
        float4 p4 = *(const float4*)(p0 + c0);
        cr[0]=r4.x; cr[1]=r4.y; cr[2]=r4.z; cr[3]=r4.w;
        cu[0]=u4.x; cu[1]=u4.y; cu[2]=u4.z; cu[3]=u4.w;
        cp[0]=p4.x; cp[1]=p4.y; cp[2]=p4.z; cp[3]=p4.w;
        float nm = 0.f;
        #pragma unroll
        for (int c = 0; c < 4; ++c) {
            float E = cp[c] * IGM1 + 0.5f * cr[c] * cu[c] * cu[c];
            float q = frsq(cr[c]);
            cE[c] = E;
            cs[c] = cr[c] * q;
            cg[c] = (E + cp[c]) * q;
            nm = fmaxf(nm, fabsf(cu[c]) + fsqrt_(GAM * cp[c] * (q * q)));
        }
        Lr[tid]=cr[3]; Lu[tid]=cu[3]; Lp[tid]=cp[3];
        if (tid == 0) {                      // left seam packet, tag 0
            u64* pk = ring_pkt(ring, 0, lb, 0);
            st_rlx64(pk, pack2f(cr[0], cu[0]));
            drain_vmem();
            st_rlx64(pk + 1, packft(cp[0], 0u));
        }
        if (tid == ABLK - 1) {               // right seam packet, tag 0
            u64* pk = ring_pkt(ring, 0, lb, 1);
            st_rlx64(pk, pack2f(cr[3], cu[3]));
            drain_vmem();
            st_rlx64(pk + 1, packft(cp[3], 0u));
        }
        nm = wave_max(nm);
        if (lane == 0) red[wid] = nm;
        __syncthreads();
        if (wid == 8 && lane < ABLK / 64) {   // publisher = wave 8
            float bm = red[lane];
            bm = fmaxf(bm, __shfl_xor(bm, 8));
            bm = fmaxf(bm, __shfl_xor(bm, 4));
            bm = fmaxf(bm, __shfl_xor(bm, 2));
            bm = fmaxf(bm, __shfl_xor(bm, 1));
            if (lane == 0) devstoreu(&bmax[lb], __float_as_uint(bm)); // sign clear
        }
    }
    float t = 0.f;
    const float tfin = *tf;

    for (int k = 0; k < NSTEPS; ++k) {
        // dt gate with one full step of slack (r19 semantics, verified).
        const unsigned* brdt = bmax + (size_t)(k > 0 ? k - 1 : 0) * ANBLK;
        float Fr[5], Fm[5], Fe[5];

        // A0. wave 4: PRE-ISSUE the dt flag loads (consumed pre-BAR1 in E;
        //     ~2us of flux between issue and use hides the RT).
        unsigned pv0 = 0, pv1 = 0, pv2 = 0, pv3 = 0;
        if (wid == 4) {
            pv0 = devloadu(&brdt[lane]);
            pv1 = devloadu(&brdt[64 + lane]);
            pv2 = devloadu(&brdt[128 + lane]);
            pv3 = devloadu(&brdt[192 + lane]);
        }

        // A. seam packet polls (self-gating tags; producer published them
        //    mid-step, ~1us before its bmax flag) + reads at step top;
        //    consumed after pair1. Relaxed loads (proven r14-r26 pattern).
        float rl, ul, pl;
        float r5 = 0.f, u5 = 0.f, p5 = 0.f;
        if (tid == 0) {
            if (lb > 0) {
                const u64* pk = ring_pkt((u64*)ring, k, lb - 1, 1);
                u64 h1;
                while ((unsigned)((h1 = ld_rlx64(pk + 1)) >> 32) != (unsigned)k)
                    __builtin_amdgcn_s_sleep(1);
                asm volatile("" ::: "memory");   // compiler fence only
                u64 h0 = ld_rlx64(pk);
                rl = __uint_as_float((unsigned)h0);
                ul = __uint_as_float((unsigned)(h0 >> 32));
                pl = __uint_as_float((unsigned)h1);
            } else { rl = cr[0]; ul = cu[0]; pl = cp[0]; }
        } else { rl = Lr[tid-1]; ul = Lu[tid-1]; pl = Lp[tid-1]; }
        if (tid == ABLK - 1) {
            if (lb < ANBLK - 1) {
                const u64* pk = ring_pkt((u64*)ring, k, lb + 1, 0);
                u64 h1;
                while ((unsigned)((h1 = ld_rlx64(pk + 1)) >> 32) != (unsigned)k)
                    __builtin_amdgcn_s_sleep(1);
                asm volatile("" ::: "memory");   // compiler fence only
                u64 h0 = ld_rlx64(pk);
                r5 = __uint_as_float((unsigned)h0);
                u5 = __uint_as_float((unsigned)(h0 >> 32));
                p5 = __uint_as_float((unsigned)h1);
            } else { r5 = cr[3]; u5 = cu[3]; p5 = cp[3]; }
        }

        // B. pair1 = interfaces (I1: c0|c1, I2: c1|c2), register-only --
        //    hides A's load latency, on the packed fp32 pipe.
        f2 Fr12, Fm12, Fe12;
        roe2(mkf2(cr[0],cr[1]), mkf2(cu[0],cu[1]), mkf2(cp[0],cp[1]),
             mkf2(cs[0],cs[1]), mkf2(cg[0],cg[1]),
             mkf2(cr[1],cr[2]), mkf2(cu[1],cu[2]), mkf2(cp[1],cp[2]),
             mkf2(cs[1],cs[2]), mkf2(cg[1],cg[2]),
             Fr12, Fm12, Fe12);
        Fr[1] = Fr12.x; Fm[1] = Fm12.x; Fe[1] = Fe12.x;
        Fr[2] = Fr12.y; Fm[2] = Fm12.y; Fe[2] = Fe12.y;

        // C. left cell s,g; pair2 = (I3: c2|c3, I0: left|c0); flux0 -> LDS
        {
            float El = pl * IGM1 + 0.5f * rl * ul * ul;
            float ql = frsq(rl);
            float sl = rl * ql, gl = (El + pl) * ql;
            f2 Fr30, Fm30, Fe30;
            roe2(mkf2(cr[2], rl), mkf2(cu[2], ul), mkf2(cp[2], pl),
                 mkf2(cs[2], sl), mkf2(cg[2], gl),
                 mkf2(cr[3], cr[0]), mkf2(cu[3], cu[0]), mkf2(cp[3], cp[0]),
                 mkf2(cs[3], cs[0]), mkf2(cg[3], cg[0]),
                 Fr30, Fm30, Fe30);
            Fr[3] = Fr30.x; Fm[3] = Fm30.x; Fe[3] = Fe30.x;
            Fr[0] = Fr30.y; Fm[0] = Fm30.y; Fe[0] = Fe30.y;
            fxr[tid] = Fr[0]; fxm[tid] = Fm[0]; fxe[tid] = Fe[0];
        }

        // D. right edge only: flux4 (seam read issued in A), scalar.
        if (tid == ABLK - 1) {
            float E5 = p5 * IGM1 + 0.5f * r5 * u5 * u5;
            float q5 = frsq(r5);
            float s5 = r5 * q5, g5 = (E5 + p5) * q5;
            roe(cr[3],cu[3],cp[3],cs[3],cg[3], r5,u5,p5,s5,g5,
                Fr[4], Fm[4], Fe[4]);
        }

        // E. wave 4: consume the pre-issued dt flags (first-try in steady
        //    state; fallback re-poll). Same reduction tree as r26 =>
        //    bit-identical dt. Overlaps wave0/wave15's seam RTs.
        if (wid == 4) {
            while (!__all(((pv0 | pv1 | pv2 | pv3) & 0x80000000u) == 0u)) {
                __builtin_amdgcn_s_sleep(1);
                pv0 = devloadu(&brdt[lane]);
                pv1 = devloadu(&brdt[64 + lane]);
                pv2 = devloadu(&brdt[128 + lane]);
                pv3 = devloadu(&brdt[192 + lane]);
            }
            float m = fmaxf(fmaxf(__uint_as_float(pv0), __uint_as_float(pv1)),
                            fmaxf(__uint_as_float(pv2), __uint_as_float(pv3)));
            m = wave_max(m);
            if (lane == 0) samax = m;
        }

        __syncthreads();   // #1: samax + flux LDS ready; Lr reads done

        if (tid < ABLK - 1) {
            Fr[4] = fxr[tid + 1]; Fm[4] = fxm[tid + 1]; Fe[4] = fxe[tid + 1];
        }
        float amax = samax;
        float dt = fminf((CFLC * DXC) * frcp(amax), fmaxf(tfin - t, 0.f));
        t += dt;
        float dtdx = dt * IDXC;

        // Update as two float2 packs: cells (0,1) and (2,3).
        f2 dtv = mkf2(dtdx, dtdx);
        f2 rA = mkf2(cr[0],cr[1]), uA = mkf2(cu[0],cu[1]), EA = mkf2(cE[0],cE[1]);
        f2 rB = mkf2(cr[2],cr[3]), uB = mkf2(cu[2],cu[3]), EB = mkf2(cE[2],cE[3]);
        f2 r2A = rA      - dtv * (mkf2(Fr[1],Fr[2]) - mkf2(Fr[0],Fr[1]));
        f2 m2A = rA * uA - dtv * (mkf2(Fm[1],Fm[2]) - mkf2(Fm[0],Fm[1]));
        f2 E2A = EA      - dtv * (mkf2(Fe[1],Fe[2]) - mkf2(Fe[0],Fe[1]));
        f2 r2B = rB      - dtv * (mkf2(Fr[3],Fr[4]) - mkf2(Fr[2],Fr[3]));
        f2 m2B = rB * uB - dtv * (mkf2(Fm[3],Fm[4]) - mkf2(Fm[2],Fm[3]));
        f2 E2B = EB      - dtv * (mkf2(Fe[3],Fe[4]) - mkf2(Fe[2],Fe[3]));
        f2 q2A = f2rsq(r2A), q2B = f2rsq(r2B);
        f2 irA = q2A * q2A,  irB = q2B * q2B;
        f2 u2A = m2A * irA,  u2B = m2B * irB;
        f2 p2A = GM1 * (E2A - 0.5f * r2A * u2A * u2A);
        f2 p2B = GM1 * (E2B - 0.5f * r2B * u2B * u2B);
        f2 nmA = f2abs(u2A) + f2sqrt(GAM * p2A * irA);
        f2 nmB = f2abs(u2B) + f2sqrt(GAM * p2B * irB);
        f2 sA = r2A * q2A, sB = r2B * q2B;
        f2 gA = (E2A + p2A) * q2A, gB = (E2B + p2B) * q2B;
        cr[0]=r2A.x; cr[1]=r2A.y; cr[2]=r2B.x; cr[3]=r2B.y;
        cu[0]=u2A.x; cu[1]=u2A.y; cu[2]=u2B.x; cu[3]=u2B.y;
        cp[0]=p2A.x; cp[1]=p2A.y; cp[2]=p2B.x; cp[3]=p2B.y;
        cE[0]=E2A.x; cE[1]=E2A.y; cE[2]=E2B.x; cE[3]=E2B.y;
        cs[0]=sA.x;  cs[1]=sA.y;  cs[2]=sB.x;  cs[3]=sB.y;
        cg[0]=gA.x;  cg[1]=gA.y;  cg[2]=gB.x;  cg[3]=gB.y;
        float nm = fmaxf(fmaxf(nmA.x, nmA.y), fmaxf(nmB.x, nmB.y));

        if (k < NSTEPS - 1) {
            // EARLY seam publish: right after the update, BEFORE the
            // reduction and barrier #2. Lightweight ordering only.
            if (tid == 0) {
                u64* pk = ring_pkt(ring, k + 1, lb, 0);
                st_rlx64(pk, pack2f(cr[0], cu[0]));
                drain_vmem();
                st_rlx64(pk + 1, packft(cp[0], (unsigned)(k + 1)));
            }
            if (tid == ABLK - 1) {
                u64* pk = ring_pkt(ring, k + 1, lb, 1);
                st_rlx64(pk, pack2f(cr[3], cu[3]));
                drain_vmem();
                st_rlx64(pk + 1, packft(cp[3], (unsigned)(k + 1)));
            }
            Lr[tid]=cr[3]; Lu[tid]=cu[3]; Lp[tid]=cp[3];
            nm = wave_max(nm);
            if (lane == 0) red[wid] = nm;
            __syncthreads();   // #2: LDS ready for k+1; red[] complete
            if (wid == 8 && lane < ABLK / 64) {   // publisher = wave 8
                float bm = red[lane];
                bm = fmaxf(bm, __shfl_xor(bm, 8));
                bm = fmaxf(bm, __shfl_xor(bm, 4));
                bm = fmaxf(bm, __shfl_xor(bm, 2));
                bm = fmaxf(bm, __shfl_xor(bm, 1));
                if (lane == 0)
                    devstoreu(&bmax[(size_t)(k + 1) * ANBLK + lb],
                              __float_as_uint(bm));          // sign clear
            }
        } else {
            *(float4*)(out + c0)         = make_float4(cr[0], cr[1], cr[2], cr[3]);
            *(float4*)(out + NXC + c0)   = make_float4(cu[0], cu[1], cu[2], cu[3]);
            *(float4*)(out + 2*NXC + c0) = make_float4(cp[0], cp[1], cp[2], cp[3]);
        }
    }
}

extern "C" void kernel_launch(void* const* d_in, const int* in_sizes, int n_in,
                              void* d_out, int out_size, void* d_ws, size_t ws_size,
                              hipStream_t stream) {
    const float* rho0 = (const float*)d_in[0];
    const float* u0   = (const float*)d_in[1];
    const float* p0   = (const float*)d_in[2];
    const float* tf   = (const float*)d_in[3];
    // d_in[4] = n_steps (fixed at 32)

    float* out      = (float*)d_out;
    unsigned* bmax  = (unsigned*)d_ws;              // 33*256 flag words
    u64* ring       = (u64*)(bmax + CTRL_TOTAL);    // 4*256*2 packets (8B-aligned)

    ctrl_init<<<(INIT_WORDS + 255) / 256, 256, 0, stream>>>(bmax);

    // Unconditional cooperative launch, 256 blocks (grids >256 are
    // rejected by the cooperative validator -- r17/r24 lesson).
    void* args[] = {(void*)&rho0, (void*)&u0, (void*)&p0, (void*)&tf,
                    (void*)&out, (void*)&bmax, (void*)&ring};
    hipLaunchCooperativeKernel((void*)euler_async, dim3(ANBLK), dim3(ABLK),
                               args, 0, stream);
}

// Round 14
// 192.436 us; speedup vs baseline: 1.0692x; 1.0692x over previous
//
#include <hip/hip_runtime.h>

// 1D Euler, Roe flux + Harten entropy fix, 32 fused steps. Round 28 = r26
// byte-for-byte (best verified: 118.3us dispatch, absmax 0.0078125).
// r27 (dt poll -> wave4 pre-issued, publish -> wave8) regressed ~+4us:
// 4th confirmation that every perturbation of this sync schedule loses
// (r15, r22, r27 placements; r20/r21 structure). Locking in the optimum.
//
// Final-state summary of the session:
//  - skeleton: 256 blocks x 1024 thr (cooperative; >256 blocks rejected
//    by the validator -- r17/r24), 4 cells/thread in registers, LDS
//    exchange for intra-block seams, 2 barriers/step.
//  - seam exchange: self-gating u64 ring packets {r,u}+{p,tag}, published
//    EARLY (right after the cell update, before reduction/BAR2) with
//    relaxed agent-scope stores + inline vmcnt drain for ordering
//    (acq/rel = L2 writeback/invalidate machinery cost 6x -- r25).
//  - dt gate: bmax row k-1 (one full step of slack, r19), polled by
//    wave0 at phase E, samax LDS broadcast.
//  - math: packed fp32 (ext_vector_type(2) -> v_pk_*) roe2 over 4
//    independent interfaces + f2-packed update (r23: busy*dur 85->69us).
//  - XCD-swizzled block ids, device-scope atomics (r18: traffic win).
// Remaining structure: ~69us genuine packed-VALU work + ~1.5us/step
// barrier spread & RT floor at 4 waves/SIMD (launcher-capped occupancy).

#define NXC   1048576
#define GAM   1.4f
#define GM1   0.4f
#define IGM1  2.5f
#define CFLC  0.5f
#define DXC   1e-3f
#define IDXC  1000.0f
#define EFIX  0.1f
#define NSTEPS 32
#define NSLOT  (NSTEPS + 1)

#define ABLK  1024
#define ACPT  4
#define ATILE (ABLK*ACPT)      // 4096
#define ANBLK (NXC/ATILE)      // 256 blocks = 1/CU (proven residency)

#define CTRL_TOTAL (NSLOT * ANBLK)          // bmax flag words
#define RING_U64   (4 * ANBLK * 2 * 2)      // 4 rows x 256 blk x 2 edges x 2 words
#define INIT_WORDS (CTRL_TOTAL + RING_U64 * 2)

typedef float f2 __attribute__((ext_vector_type(2)));
typedef unsigned long long u64;

__device__ __forceinline__ float frcp(float x){ return __builtin_amdgcn_rcpf(x); }
__device__ __forceinline__ float frsq(float x){ return __builtin_amdgcn_rsqf(x); }
__device__ __forceinline__ float fsqrt_(float x){ return __builtin_amdgcn_sqrtf(x); }

__device__ __forceinline__ f2 mkf2(float a, float b){ f2 v; v.x=a; v.y=b; return v; }
__device__ __forceinline__ f2 f2rcp(f2 a){ return mkf2(frcp(a.x), frcp(a.y)); }
__device__ __forceinline__ f2 f2rsq(f2 a){ return mkf2(frsq(a.x), frsq(a.y)); }
__device__ __forceinline__ f2 f2sqrt(f2 a){ return mkf2(fsqrt_(a.x), fsqrt_(a.y)); }
__device__ __forceinline__ f2 f2max(f2 a, f2 b){
    return mkf2(fmaxf(a.x,b.x), fmaxf(a.y,b.y));
}
__device__ __forceinline__ f2 f2abs(f2 a){
    return mkf2(fabsf(a.x), fabsf(a.y));
}

// Device (agent) scope RELAXED atomics only -- no acq/rel machinery.
__device__ __forceinline__ unsigned devloadu(const unsigned* p) {
    return __hip_atomic_load(p, __ATOMIC_RELAXED, __HIP_MEMORY_SCOPE_AGENT);
}
__device__ __forceinline__ void devstoreu(unsigned* p, unsigned v) {
    __hip_atomic_store(p, v, __ATOMIC_RELAXED, __HIP_MEMORY_SCOPE_AGENT);
}
__device__ __forceinline__ u64 ld_rlx64(const u64* p) {
    return __hip_atomic_load(p, __ATOMIC_RELAXED, __HIP_MEMORY_SCOPE_AGENT);
}
__device__ __forceinline__ void st_rlx64(u64* p, u64 v) {
    __hip_atomic_store(p, v, __ATOMIC_RELAXED, __HIP_MEMORY_SCOPE_AGENT);
}
__device__ __forceinline__ void drain_vmem() {
    // Producer-side ordering: data word complete at the coherence point
    // before the tag word issues (the proven r26 mechanism).
    asm volatile("s_waitcnt vmcnt(0)" ::: "memory");
}
__device__ __forceinline__ u64 pack2f(float a, float b) {
    return (u64)__float_as_uint(a) | ((u64)__float_as_uint(b) << 32);
}
__device__ __forceinline__ u64 packft(float a, unsigned tag) {
    return (u64)__float_as_uint(a) | ((u64)tag << 32);
}

__device__ __forceinline__ float wave_max(float v) {
    #pragma unroll
    for (int k = 32; k >= 1; k >>= 1)
        v = fmaxf(v, __shfl_xor(v, k));
    return v;
}

// Sentinel init: bmax flags sign-SET ("unpublished"); ring tags != any k.
__global__ void ctrl_init(unsigned* z) {
    int i = blockIdx.x * 256 + threadIdx.x;
    if (i < INIT_WORDS) z[i] = 0xAAAAAAAAu;
}

// Scalar Roe flux (right-edge interface only).
__device__ __forceinline__ void roe(
        float rL, float uL, float pL, float sL, float gL,
        float rR, float uR, float pR, float sR, float gR,
        float& Frj, float& Fmj, float& Fej) {
    float invden = frcp(sL + sR);
    float ur = (sL * uL + sR * uR) * invden;
    float Hr = (gL + gR) * invden;
    float c2u = fmaxf(GM1 * (Hr - 0.5f * ur * ur), 1e-10f);
    float qc = frsq(c2u);
    float c  = c2u * qc;
    float inv2c2 = 0.5f * qc * qc;
    float eps = EFIX * c;
    float l1 = ur - c, l3 = ur + c;
    float a1 = fsqrt_(l1 * l1 + eps * eps);
    float a2 = fsqrt_(ur * ur + eps * eps);
    float a3 = fsqrt_(l3 * l3 + eps * eps);
    float drho = rR - rL;
    float du   = uR - uL;
    float dp   = pR - pL;
    float al2 = drho - (dp + dp) * inv2c2;
    float tcd = c * rR * du;
    float al1 = (dp - tcd) * inv2c2;
    float al3 = (dp + tcd) * inv2c2;
    float FrL = rL * uL, FrR = rR * uR;
    float FmL = FrL * uL + pL, FmR = FrR * uR + pR;
    float FeL = uL * (gL * sL), FeR = uR * (gR * sR);
    float w1 = a1 * al1, w2 = a2 * al2, w3 = a3 * al3;
    Frj = 0.5f * (FrL + FrR - (w1 + w2 + w3));
    Fmj = 0.5f * (FmL + FmR - (w1 * l1 + w2 * ur + w3 * l3));
    Fej = 0.5f * (FeL + FeR - (w1 * (Hr - ur * c) + w2 * (0.5f * ur * ur)
                               + w3 * (Hr + ur * c)));
}

// Packed Roe flux: two independent interfaces per call (v_pk_* fp32 path).
__device__ __forceinline__ void roe2(
        f2 rL, f2 uL, f2 pL, f2 sL, f2 gL,
        f2 rR, f2 uR, f2 pR, f2 sR, f2 gR,
        f2& Frj, f2& Fmj, f2& Fej) {
    f2 invden = f2rcp(sL + sR);
    f2 ur = (sL * uL + sR * uR) * invden;
    f2 Hr = (gL + gR) * invden;
    f2 c2u = f2max(GM1 * (Hr - 0.5f * ur * ur), mkf2(1e-10f, 1e-10f));
    f2 qc = f2rsq(c2u);
    f2 c  = c2u * qc;
    f2 inv2c2 = 0.5f * qc * qc;
    f2 eps = EFIX * c;
    f2 l1 = ur - c, l3 = ur + c;
    f2 a1 = f2sqrt(l1 * l1 + eps * eps);
    f2 a2 = f2sqrt(ur * ur + eps * eps);
    f2 a3 = f2sqrt(l3 * l3 + eps * eps);
    f2 drho = rR - rL;
    f2 du   = uR - uL;
    f2 dp   = pR - pL;
    f2 al2 = drho - (dp + dp) * inv2c2;
    f2 tcd = c * rR * du;
    f2 al1 = (dp - tcd) * inv2c2;
    f2 al3 = (dp + tcd) * inv2c2;
    f2 FrL = rL * uL, FrR = rR * uR;
    f2 FmL = FrL * uL + pL, FmR = FrR * uR + pR;
    f2 FeL = uL * (gL * sL), FeR = uR * (gR * sR);
    f2 w1 = a1 * al1, w2 = a2 * al2, w3 = a3 * al3;
    Frj = 0.5f * (FrL + FrR - (w1 + w2 + w3));
    Fmj = 0.5f * (FmL + FmR - (w1 * l1 + w2 * ur + w3 * l3));
    Fej = 0.5f * (FeL + FeR - (w1 * (Hr - ur * c) + w2 * (0.5f * ur * ur)
                               + w3 * (Hr + ur * c)));
}

// ring layout: [(row&3)][block][edge][word]; edge 0 = cell0 (left),
// edge 1 = cell3 (right); word 0 = {r,u}, word 1 = {p, tag}.
__device__ __forceinline__ u64* ring_pkt(u64* ring, int row, int blk, int edge) {
    return ring + (((size_t)(row & 3) * ANBLK + blk) * 2 + edge) * 2;
}

__global__ __launch_bounds__(ABLK, 4) void euler_async(
        const float* __restrict__ rho0, const float* __restrict__ u0,
        const float* __restrict__ p0, const float* __restrict__ tf,
        float* __restrict__ out, unsigned* __restrict__ bmax,
        u64* __restrict__ ring) {
    __shared__ float Lr[ABLK], Lu[ABLK], Lp[ABLK];    // each thread's cell3
    __shared__ float fxr[ABLK], fxm[ABLK], fxe[ABLK]; // each thread's flux0
    __shared__ float red[ABLK / 64];
    __shared__ float samax;

    const int tid = threadIdx.x;
    // XCD swizzle (kept from r18: time-neutral, lowers L2 misses).
    const int lb = (blockIdx.x & 7) * (ANBLK / 8) + (blockIdx.x >> 3);
    const int c0 = lb * ATILE + ACPT * tid;
    const int lane = tid & 63, wid = tid >> 6;

    float cr[4], cu[4], cp[4], cE[4], cs[4], cg[4];

    // ---- prepass: inputs -> regs (incl E,s,g); publish seam row 0 +
    // bmax row 0 --
    {
        float4 r4 = *(const float4*)(rho0 + c0);
        float4 u4 = *(const float4*)(u0 + c0);
        float4 p4 = *(const float4*)(p0 + c0);
        cr[0]=r4.x; cr[1]=r4.y; cr[2]=r4.z; cr[3]=r4.w;
        cu[0]=u4.x; cu[1]=u4.y; cu[2]=u4.z; cu[3]=u4.w;
        cp[0]=p4.x; cp[1]=p4.y; cp[2]=p4.z; cp[3]=p4.w;
        float nm = 0.f;
        #pragma unroll
        for (int c = 0; c < 4; ++c) {
            float E = cp[c] * IGM1 + 0.5f * cr[c] * cu[c] * cu[c];
            float q = frsq(cr[c]);
            cE[c] = E;
            cs[c] = cr[c] * q;
            cg[c] = (E + cp[c]) * q;
            nm = fmaxf(nm, fabsf(cu[c]) + fsqrt_(GAM * cp[c] * (q * q)));
        }
        Lr[tid]=cr[3]; Lu[tid]=cu[3]; Lp[tid]=cp[3];
        if (tid == 0) {                      // left seam packet, tag 0
            u64* pk = ring_pkt(ring, 0, lb, 0);
            st_rlx64(pk, pack2f(cr[0], cu[0]));
            drain_vmem();
            st_rlx64(pk + 1, packft(cp[0], 0u));
        }
        if (tid == ABLK - 1) {               // right seam packet, tag 0
            u64* pk = ring_pkt(ring, 0, lb, 1);
            st_rlx64(pk, pack2f(cr[3], cu[3]));
            drain_vmem();
            st_rlx64(pk + 1, packft(cp[3], 0u));
        }
        nm = wave_max(nm);
        if (lane == 0) red[wid] = nm;
        __syncthreads();
        if (tid < ABLK / 64) {
            float bm = red[tid];
            bm = fmaxf(bm, __shfl_xor(bm, 8));
            bm = fmaxf(bm, __shfl_xor(bm, 4));
            bm = fmaxf(bm, __shfl_xor(bm, 2));
            bm = fmaxf(bm, __shfl_xor(bm, 1));
            if (tid == 0) devstoreu(&bmax[lb], __float_as_uint(bm)); // sign clear
        }
    }
    float t = 0.f;
    const float tfin = *tf;

    for (int k = 0; k < NSTEPS; ++k) {
        // dt gate with one full step of slack (r19 semantics, verified).
        const unsigned* brdt = bmax + (size_t)(k > 0 ? k - 1 : 0) * ANBLK;
        float Fr[5], Fm[5], Fe[5];

        // A. seam packet polls (self-gating tags; producer published them
        //    mid-step, ~1us before its bmax flag) + reads at step top;
        //    consumed after pair1. Relaxed loads (proven r14-r26 pattern).
        float rl, ul, pl;
        float r5 = 0.f, u5 = 0.f, p5 = 0.f;
        if (tid == 0) {
            if (lb > 0) {
                const u64* pk = ring_pkt((u64*)ring, k, lb - 1, 1);
                u64 h1;
                while ((unsigned)((h1 = ld_rlx64(pk + 1)) >> 32) != (unsigned)k)
                    __builtin_amdgcn_s_sleep(1);
                asm volatile("" ::: "memory");   // compiler fence only
                u64 h0 = ld_rlx64(pk);
                rl = __uint_as_float((unsigned)h0);
                ul = __uint_as_float((unsigned)(h0 >> 32));
                pl = __uint_as_float((unsigned)h1);
            } else { rl = cr[0]; ul = cu[0]; pl = cp[0]; }
        } else { rl = Lr[tid-1]; ul = Lu[tid-1]; pl = Lp[tid-1]; }
        if (tid == ABLK - 1) {
            if (lb < ANBLK - 1) {
                const u64* pk = ring_pkt((u64*)ring, k, lb + 1, 0);
                u64 h1;
                while ((unsigned)((h1 = ld_rlx64(pk + 1)) >> 32) != (unsigned)k)
                    __builtin_amdgcn_s_sleep(1);
                asm volatile("" ::: "memory");   // compiler fence only
                u64 h0 = ld_rlx64(pk);
                r5 = __uint_as_float((unsigned)h0);
                u5 = __uint_as_float((unsigned)(h0 >> 32));
                p5 = __uint_as_float((unsigned)h1);
            } else { r5 = cr[3]; u5 = cu[3]; p5 = cp[3]; }
        }

        // B. pair1 = interfaces (I1: c0|c1, I2: c1|c2), register-only --
        //    hides A's load latency, on the packed fp32 pipe.
        f2 Fr12, Fm12, Fe12;
        roe2(mkf2(cr[0],cr[1]), mkf2(cu[0],cu[1]), mkf2(cp[0],cp[1]),
             mkf2(cs[0],cs[1]), mkf2(cg[0],cg[1]),
             mkf2(cr[1],cr[2]), mkf2(cu[1],cu[2]), mkf2(cp[1],cp[2]),
             mkf2(cs[1],cs[2]), mkf2(cg[1],cg[2]),
             Fr12, Fm12, Fe12);
        Fr[1] = Fr12.x; Fm[1] = Fm12.x; Fe[1] = Fe12.x;
        Fr[2] = Fr12.y; Fm[2] = Fm12.y; Fe[2] = Fe12.y;

        // C. left cell s,g; pair2 = (I3: c2|c3, I0: left|c0); flux0 -> LDS
        {
            float El = pl * IGM1 + 0.5f * rl * ul * ul;
            float ql = frsq(rl);
            float sl = rl * ql, gl = (El + pl) * ql;
            f2 Fr30, Fm30, Fe30;
            roe2(mkf2(cr[2], rl), mkf2(cu[2], ul), mkf2(cp[2], pl),
                 mkf2(cs[2], sl), mkf2(cg[2], gl),
                 mkf2(cr[3], cr[0]), mkf2(cu[3], cu[0]), mkf2(cp[3], cp[0]),
                 mkf2(cs[3], cs[0]), mkf2(cg[3], cg[0]),
                 Fr30, Fm30, Fe30);
            Fr[3] = Fr30.x; Fm[3] = Fm30.x; Fe[3] = Fe30.x;
            Fr[0] = Fr30.y; Fm[0] = Fm30.y; Fe[0] = Fe30.y;
            fxr[tid] = Fr[0]; fxm[tid] = Fm[0]; fxe[tid] = Fe[0];
        }

        // D. right edge only: flux4 (seam read issued in A), scalar.
        if (tid == ABLK - 1) {
            float E5 = p5 * IGM1 + 0.5f * r5 * u5 * u5;
            float q5 = frsq(r5);
            float s5 = r5 * q5, g5 = (E5 + p5) * q5;
            roe(cr[3],cu[3],cp[3],cs[3],cg[3], r5,u5,p5,s5,g5,
                Fr[4], Fm[4], Fe[4]);
        }

        // E. wave0: dt poll over the slack row (first-try in steady state)
        if (wid == 0) {
            unsigned v0, v1, v2, v3;
            for (;;) {
                v0 = devloadu(&brdt[lane]);
                v1 = devloadu(&brdt[64 + lane]);
                v2 = devloadu(&brdt[128 + lane]);
                v3 = devloadu(&brdt[192 + lane]);
                if (__all(((v0 | v1 | v2 | v3) & 0x80000000u) == 0u)) break;
                __builtin_amdgcn_s_sleep(1);
            }
            float m = fmaxf(fmaxf(__uint_as_float(v0), __uint_as_float(v1)),
                            fmaxf(__uint_as_float(v2), __uint_as_float(v3)));
            m = wave_max(m);
            if (lane == 0) samax = m;
        }

        __syncthreads();   // #1: samax + flux LDS ready; Lr reads done

        if (tid < ABLK - 1) {
            Fr[4] = fxr[tid + 1]; Fm[4] = fxm[tid + 1]; Fe[4] = fxe[tid + 1];
        }
        float amax = samax;
        float dt = fminf((CFLC * DXC) * frcp(amax), fmaxf(tfin - t, 0.f));
        t += dt;
        float dtdx = dt * IDXC;

        // Update as two float2 packs: cells (0,1) and (2,3).
        f2 dtv = mkf2(dtdx, dtdx);
        f2 rA = mkf2(cr[0],cr[1]), uA = mkf2(cu[0],cu[1]), EA = mkf2(cE[0],cE[1]);
        f2 rB = mkf2(cr[2],cr[3]), uB = mkf2(cu[2],cu[3]), EB = mkf2(cE[2],cE[3]);
        f2 r2A = rA      - dtv * (mkf2(Fr[1],Fr[2]) - mkf2(Fr[0],Fr[1]));
        f2 m2A = rA * uA - dtv * (mkf2(Fm[1],Fm[2]) - mkf2(Fm[0],Fm[1]));
        f2 E2A = EA      - dtv * (mkf2(Fe[1],Fe[2]) - mkf2(Fe[0],Fe[1]));
        f2 r2B = rB      - dtv * (mkf2(Fr[3],Fr[4]) - mkf2(Fr[2],Fr[3]));
        f2 m2B = rB * uB - dtv * (mkf2(Fm[3],Fm[4]) - mkf2(Fm[2],Fm[3]));
        f2 E2B = EB      - dtv * (mkf2(Fe[3],Fe[4]) - mkf2(Fe[2],Fe[3]));
        f2 q2A = f2rsq(r2A), q2B = f2rsq(r2B);
        f2 irA = q2A * q2A,  irB = q2B * q2B;
        f2 u2A = m2A * irA,  u2B = m2B * irB;
        f2 p2A = GM1 * (E2A - 0.5f * r2A * u2A * u2A);
        f2 p2B = GM1 * (E2B - 0.5f * r2B * u2B * u2B);
        f2 nmA = f2abs(u2A) + f2sqrt(GAM * p2A * irA);
        f2 nmB = f2abs(u2B) + f2sqrt(GAM * p2B * irB);
        f2 sA = r2A * q2A, sB = r2B * q2B;
        f2 gA = (E2A + p2A) * q2A, gB = (E2B + p2B) * q2B;
        cr[0]=r2A.x; cr[1]=r2A.y; cr[2]=r2B.x; cr[3]=r2B.y;
        cu[0]=u2A.x; cu[1]=u2A.y; cu[2]=u2B.x; cu[3]=u2B.y;
        cp[0]=p2A.x; cp[1]=p2A.y; cp[2]=p2B.x; cp[3]=p2B.y;
        cE[0]=E2A.x; cE[1]=E2A.y; cE[2]=E2B.x; cE[3]=E2B.y;
        cs[0]=sA.x;  cs[1]=sA.y;  cs[2]=sB.x;  cs[3]=sB.y;
        cg[0]=gA.x;  cg[1]=gA.y;  cg[2]=gB.x;  cg[3]=gB.y;
        float nm = fmaxf(fmaxf(nmA.x, nmA.y), fmaxf(nmB.x, nmB.y));

        if (k < NSTEPS - 1) {
            // EARLY seam publish: right after the update, BEFORE the
            // reduction and barrier #2. Lightweight ordering only.
            if (tid == 0) {
                u64* pk = ring_pkt(ring, k + 1, lb, 0);
                st_rlx64(pk, pack2f(cr[0], cu[0]));
                drain_vmem();
                st_rlx64(pk + 1, packft(cp[0], (unsigned)(k + 1)));
            }
            if (tid == ABLK - 1) {
                u64* pk = ring_pkt(ring, k + 1, lb, 1);
                st_rlx64(pk, pack2f(cr[3], cu[3]));
                drain_vmem();
                st_rlx64(pk + 1, packft(cp[3], (unsigned)(k + 1)));
            }
            Lr[tid]=cr[3]; Lu[tid]=cu[3]; Lp[tid]=cp[3];
            nm = wave_max(nm);
            if (lane == 0) red[wid] = nm;
            __syncthreads();   // #2: LDS ready for k+1; red[] complete
            if (tid < ABLK / 64) {
                float bm = red[tid];
                bm = fmaxf(bm, __shfl_xor(bm, 8));
                bm = fmaxf(bm, __shfl_xor(bm, 4));
                bm = fmaxf(bm, __shfl_xor(bm, 2));
                bm = fmaxf(bm, __shfl_xor(bm, 1));
                if (tid == 0)
                    devstoreu(&bmax[(size_t)(k + 1) * ANBLK + lb],
                              __float_as_uint(bm));          // sign clear
            }
        } else {
            *(float4*)(out + c0)         = make_float4(cr[0], cr[1], cr[2], cr[3]);
            *(float4*)(out + NXC + c0)   = make_float4(cu[0], cu[1], cu[2], cu[3]);
            *(float4*)(out + 2*NXC + c0) = make_float4(cp[0], cp[1], cp[2], cp[3]);
        }
    }
}

extern "C" void kernel_launch(void* const* d_in, const int* in_sizes, int n_in,
                              void* d_out, int out_size, void* d_ws, size_t ws_size,
                              hipStream_t stream) {
    const float* rho0 = (const float*)d_in[0];
    const float* u0   = (const float*)d_in[1];
    const float* p0   = (const float*)d_in[2];
    const float* tf   = (const float*)d_in[3];
    // d_in[4] = n_steps (fixed at 32)

    float* out      = (float*)d_out;
    unsigned* bmax  = (unsigned*)d_ws;              // 33*256 flag words
    u64* ring       = (u64*)(bmax + CTRL_TOTAL);    // 4*256*2 packets (8B-aligned)

    ctrl_init<<<(INIT_WORDS + 255) / 256, 256, 0, stream>>>(bmax);

    // Unconditional cooperative launch, 256 blocks (grids >256 are
    // rejected by the cooperative validator -- r17/r24 lesson).
    void* args[] = {(void*)&rho0, (void*)&u0, (void*)&p0, (void*)&tf,
                    (void*)&out, (void*)&bmax, (void*)&ring};
    hipLaunchCooperativeKernel((void*)euler_async, dim3(ANBLK), dim3(ABLK),
                               args, 0, stream);
}